// Round 11
// baseline (218.938 us; speedup 1.0000x reference)
//
#include <hip/hip_runtime.h>
#include <math.h>

#define D_MODEL 1024
#define D_STATE 16
#define BATCH   2
#define SEQ     2048
#define M_ROWS  (BATCH*SEQ)   // 4096
#define KP      3072          // split K' = 3*1024
#define CH      16            // scan chunk length
#define NCHUNK  (SEQ/CH)      // 128

typedef unsigned short ushortT;
typedef ushortT ushortx4 __attribute__((ext_vector_type(4)));
typedef ushortT ushortx8 __attribute__((ext_vector_type(8)));
typedef short   shortx8  __attribute__((ext_vector_type(8)));
typedef float   f32x4    __attribute__((ext_vector_type(4)));

__device__ __forceinline__ float silu_f(float x) {
    return x / (1.0f + __expf(-x));
}
__device__ __forceinline__ ushortT f2bf_rne(float f) {
    unsigned u = __float_as_uint(f);
    u += 0x7FFF + ((u >> 16) & 1);
    return (ushortT)(u >> 16);
}
__device__ __forceinline__ float bf2f(ushortT h) {
    return __uint_as_float(((unsigned)h) << 16);
}
__device__ __forceinline__ void gload_lds16(const void* g, void* l) {
    __builtin_amdgcn_global_load_lds(
        (const __attribute__((address_space(1))) void*)g,
        (__attribute__((address_space(3))) void*)l, 16, 0, 0);
}

// ---------------------------------------------------------------------------
// Merged prologue elementwise conversions (no LDS, no barriers):
//  blocks [0, M_ROWS)        : x [M][1024] -> Xs [M][3072] (hi|lo|hi)
//  blocks [M_ROWS, M_ROWS+256): W_xp [1024][48] -> wxp [64][3072] (hi|hi|lo)
// ---------------------------------------------------------------------------
__global__ __launch_bounds__(256)
void split_x_xp_kernel(const float* __restrict__ X, const float* __restrict__ W_xp,
                       ushortT* __restrict__ Xs, ushortT* __restrict__ wxp)
{
    const int bid = blockIdx.x;
    const int tid = threadIdx.x;
    if (bid < M_ROWS) {
        int gid = bid * 256 + tid;          // M*256
        int row = gid >> 8, kc = gid & 255;
        float4 v = *reinterpret_cast<const float4*>(X + (size_t)row * D_MODEL + kc * 4);
        float vv[4] = {v.x, v.y, v.z, v.w};
        ushortx4 h, l;
#pragma unroll
        for (int i = 0; i < 4; ++i) {
            ushortT hi = f2bf_rne(vv[i]);
            h[i] = hi;
            l[i] = f2bf_rne(vv[i] - bf2f(hi));
        }
        ushortT* base = Xs + (size_t)row * KP + kc * 4;
        *(ushortx4*)(base)               = h;
        *(ushortx4*)(base + D_MODEL)     = l;
        *(ushortx4*)(base + 2 * D_MODEL) = h;
    } else {
        int gid = (bid - M_ROWS) * 256 + tid;   // 64*1024
        int k = gid & (D_MODEL - 1);
        int n = gid >> 10;
        ushortT hi = 0, lo = 0;
        if (n < 48) {
            float v = W_xp[(size_t)k * 48 + n];
            hi = f2bf_rne(v);
            lo = f2bf_rne(v - bf2f(hi));
        }
        ushortT* base = wxp + (size_t)n * KP + k;
        base[0]           = hi;
        base[D_MODEL]     = hi;
        base[2 * D_MODEL] = lo;
    }
}

// ---------------------------------------------------------------------------
// Weight transpose + split: W fp32 [1024][N] -> Wt bf16 [N][3072] = [hi|hi|lo]
// ---------------------------------------------------------------------------
__global__ __launch_bounds__(256)
void wsplit_t_kernel(const float* __restrict__ W, ushortT* __restrict__ Wt, int N)
{
    __shared__ float tile[32][33];
    const int K = D_MODEL;
    int nb = blockIdx.x * 32, kb = blockIdx.y * 32;
    int tx = threadIdx.x & 31;
    int ty = threadIdx.x >> 5;   // 0..7
#pragma unroll
    for (int i = 0; i < 4; ++i) {
        int k = ty + i * 8;
        tile[k][tx] = W[(size_t)(kb + k) * N + nb + tx];
    }
    __syncthreads();
#pragma unroll
    for (int i = 0; i < 4; ++i) {
        int n = ty + i * 8;
        float v = tile[tx][n];
        ushortT hi = f2bf_rne(v);
        ushortT lo = f2bf_rne(v - bf2f(hi));
        ushortT* base = Wt + (size_t)(nb + n) * KP + kb + tx;
        base[0]     = hi;
        base[K]     = hi;
        base[2 * K] = lo;
    }
}

// ---------------------------------------------------------------------------
// bf16 MFMA GEMM: C = A[M][KP] @ Bt[N][KP]^T (+bias), 128x128 tile, BK=64,
// 4 waves (2x2), 16x16x32 MFMA. global_load_lds dbuf staging.
// gridDim.z==1: bias + split C0|C1 write. gridDim.z>1: K-split partials to C0.
// ---------------------------------------------------------------------------
__global__ __launch_bounds__(256)
void gemm_mfma_split(const ushortT* __restrict__ A,
                     const ushortT* __restrict__ Bt,
                     const float* __restrict__ bias,
                     float* __restrict__ C0,
                     float* __restrict__ C1,
                     int N, int split, int NS)
{
    __shared__ char lds[65536];   // [2 bufs][A 16K | B 16K]

    const int tid  = threadIdx.x;
    const int lane = tid & 63;
    const int wid  = tid >> 6;
    const int wr   = wid >> 1;
    const int wc   = wid & 1;

    const int nwg  = gridDim.x * gridDim.y;
    const int wgid = blockIdx.y * gridDim.x + blockIdx.x;
    const int qc   = nwg >> 3;
    const int swz  = (wgid & 7) * qc + (wgid >> 3);
    const int bx   = swz % gridDim.x;
    const int by   = swz / gridDim.x;
    const int brow = by * 128;
    const int bcol = bx * 128;
    const int kbeg = blockIdx.z * NS * 64;

    f32x4 acc[4][4];
#pragma unroll
    for (int i = 0; i < 4; ++i)
#pragma unroll
        for (int j = 0; j < 4; ++j) {
            acc[i][j][0] = 0.f; acc[i][j][1] = 0.f;
            acc[i][j][2] = 0.f; acc[i][j][3] = 0.f;
        }

    const ushortT* Ag = A  + (size_t)brow * KP + kbeg;
    const ushortT* Bg = Bt + (size_t)bcol * KP + kbeg;

    int off[4], lslot[4];
#pragma unroll
    for (int q = 0; q < 4; ++q) {
        int slot = q * 256 + tid;
        int row = slot >> 3, kc = slot & 7;
        off[q]   = row * KP + ((kc ^ (row & 7)) << 3);
        lslot[q] = (q * 256 + wid * 64) * 16;
    }

#define STAGE(buf, k0)                                                         \
    {                                                                          \
        char* Ad = lds + (buf) * 32768;                                        \
        char* Bd = Ad + 16384;                                                 \
        _Pragma("unroll")                                                      \
        for (int q = 0; q < 4; ++q) {                                          \
            gload_lds16(Ag + off[q] + (k0), Ad + lslot[q]);                    \
            gload_lds16(Bg + off[q] + (k0), Bd + lslot[q]);                    \
        }                                                                      \
    }

#define COMPUTE(buf)                                                           \
    {                                                                          \
        char* Asm = lds + (buf) * 32768;                                       \
        char* Bsm = Asm + 16384;                                               \
        _Pragma("unroll")                                                      \
        for (int ks = 0; ks < 2; ++ks) {                                       \
            shortx8 af[4], bfr[4];                                             \
            _Pragma("unroll")                                                  \
            for (int mt = 0; mt < 4; ++mt) {                                   \
                int row = wr * 64 + mt * 16 + (lane & 15);                     \
                int kc = ks * 4 + (lane >> 4);                                 \
                int byt = row * 128 + ((kc * 16) ^ ((row & 7) << 4));          \
                af[mt] = *(const shortx8*)(Asm + byt);                         \
            }                                                                  \
            _Pragma("unroll")                                                  \
            for (int nt = 0; nt < 4; ++nt) {                                   \
                int row = wc * 64 + nt * 16 + (lane & 15);                     \
                int kc = ks * 4 + (lane >> 4);                                 \
                int byt = row * 128 + ((kc * 16) ^ ((row & 7) << 4));          \
                bfr[nt] = *(const shortx8*)(Bsm + byt);                        \
            }                                                                  \
            _Pragma("unroll")                                                  \
            for (int mt = 0; mt < 4; ++mt)                                     \
                _Pragma("unroll")                                              \
                for (int nt = 0; nt < 4; ++nt)                                 \
                    acc[mt][nt] = __builtin_amdgcn_mfma_f32_16x16x32_bf16(     \
                        af[mt], bfr[nt], acc[mt][nt], 0, 0, 0);                \
        }                                                                      \
    }

    STAGE(0, 0);
    __syncthreads();
    for (int s = 0; s < NS; ++s) {
        const int cur = s & 1;
        if (s + 1 < NS) STAGE(cur ^ 1, (s + 1) * 64);
        COMPUTE(cur);
        __syncthreads();
    }

#undef STAGE
#undef COMPUTE

    if (gridDim.z == 1) {
        const bool inC0  = (bcol < split);
        float* dst       = inC0 ? C0 : C1;
        const int ldc    = inC0 ? split : (N - split);
        const int cb     = bcol - (inC0 ? 0 : split);
#pragma unroll
        for (int mt = 0; mt < 4; ++mt)
#pragma unroll
            for (int nt = 0; nt < 4; ++nt)
#pragma unroll
                for (int j = 0; j < 4; ++j) {
                    int r  = brow + wr * 64 + mt * 16 + (lane >> 4) * 4 + j;
                    int cg = wc * 64 + nt * 16 + (lane & 15);
                    dst[(size_t)r * ldc + cb + cg] = acc[mt][nt][j] + bias[bcol + cg];
                }
    } else {
        float* dst = C0 + (size_t)blockIdx.z * ((size_t)M_ROWS * N);
#pragma unroll
        for (int mt = 0; mt < 4; ++mt)
#pragma unroll
            for (int nt = 0; nt < 4; ++nt)
#pragma unroll
                for (int j = 0; j < 4; ++j) {
                    int r  = brow + wr * 64 + mt * 16 + (lane >> 4) * 4 + j;
                    int cg = wc * 64 + nt * 16 + (lane & 15);
                    dst[(size_t)r * N + bcol + cg] = acc[mt][nt][j];
                }
    }
}

// ---------------------------------------------------------------------------
// out = bias + part0 + part1
// ---------------------------------------------------------------------------
__global__ __launch_bounds__(256)
void out_combine_kernel(const float* __restrict__ part,
                        const float* __restrict__ bias,
                        float* __restrict__ out)
{
    int gid = blockIdx.x * 256 + threadIdx.x;   // M*256
    if (gid >= M_ROWS * 256) return;
    int row = gid >> 8, q = gid & 255;
    size_t i = (size_t)row * D_MODEL + q * 4;
    float4 b  = *reinterpret_cast<const float4*>(bias + q * 4);
    float4 p0 = *reinterpret_cast<const float4*>(part + i);
    float4 p1 = *reinterpret_cast<const float4*>(part + (size_t)M_ROWS * D_MODEL + i);
    float4 r;
    r.x = b.x + p0.x + p1.x; r.y = b.y + p0.y + p1.y;
    r.z = b.z + p0.z + p1.z; r.w = b.w + p0.w + p1.w;
    *reinterpret_cast<float4*>(out + i) = r;
}

// ---------------------------------------------------------------------------
// Skinny MFMA GEMM for x_db: A us[M][KP] @ wxp[64][KP]^T, K-split 4 ways.
// ---------------------------------------------------------------------------
__global__ __launch_bounds__(256)
void gemm_xp_mfma(const ushortT* __restrict__ A,
                  const ushortT* __restrict__ Bt,
                  float* __restrict__ Part)
{
    __shared__ char lds[24576];
    char* Asm = lds;
    char* Bsm = lds + 16384;

    const int tid  = threadIdx.x;
    const int lane = tid & 63;
    const int wid  = tid >> 6;
    const int ksp  = blockIdx.x;
    const int brow = blockIdx.y * 128;
    const int kbase = ksp * (KP / 4);

    f32x4 acc[2][4];
#pragma unroll
    for (int i = 0; i < 2; ++i)
#pragma unroll
        for (int j = 0; j < 4; ++j) {
            acc[i][j][0] = 0.f; acc[i][j][1] = 0.f;
            acc[i][j][2] = 0.f; acc[i][j][3] = 0.f;
        }

    const ushortT* Ag = A  + (size_t)brow * KP + kbase;
    const ushortT* Bg = Bt + kbase;

    for (int s = 0; s < 12; ++s) {
        const int k0 = s * 64;
        ushortx8 ra[4], rb[2];
#pragma unroll
        for (int q = 0; q < 4; ++q) {
            int slot = tid + q * 256;
            int row = slot >> 3, kc = slot & 7;
            ra[q] = *(const ushortx8*)(Ag + (size_t)row * KP + k0 + kc * 8);
        }
#pragma unroll
        for (int q = 0; q < 2; ++q) {
            int slot = tid + q * 256;
            int row = slot >> 3, kc = slot & 7;
            rb[q] = *(const ushortx8*)(Bg + (size_t)row * KP + k0 + kc * 8);
        }
        __syncthreads();
#pragma unroll
        for (int q = 0; q < 4; ++q) {
            int slot = tid + q * 256;
            int row = slot >> 3, kc = slot & 7;
            int byt = row * 128 + ((kc * 16) ^ ((row & 7) << 4));
            *(ushortx8*)(Asm + byt) = ra[q];
        }
#pragma unroll
        for (int q = 0; q < 2; ++q) {
            int slot = tid + q * 256;
            int row = slot >> 3, kc = slot & 7;
            int byt = row * 128 + ((kc * 16) ^ ((row & 7) << 4));
            *(ushortx8*)(Bsm + byt) = rb[q];
        }
        __syncthreads();
#pragma unroll
        for (int ks = 0; ks < 2; ++ks) {
            shortx8 af[2], bfr[4];
#pragma unroll
            for (int mt = 0; mt < 2; ++mt) {
                int row = wid * 32 + mt * 16 + (lane & 15);
                int kc = ks * 4 + (lane >> 4);
                int byt = row * 128 + ((kc * 16) ^ ((row & 7) << 4));
                af[mt] = *(const shortx8*)(Asm + byt);
            }
#pragma unroll
            for (int nt = 0; nt < 4; ++nt) {
                int row = nt * 16 + (lane & 15);
                int kc = ks * 4 + (lane >> 4);
                int byt = row * 128 + ((kc * 16) ^ ((row & 7) << 4));
                bfr[nt] = *(const shortx8*)(Bsm + byt);
            }
#pragma unroll
            for (int mt = 0; mt < 2; ++mt)
#pragma unroll
                for (int nt = 0; nt < 4; ++nt)
                    acc[mt][nt] = __builtin_amdgcn_mfma_f32_16x16x32_bf16(
                        af[mt], bfr[nt], acc[mt][nt], 0, 0, 0);
        }
        __syncthreads();
    }

    float* dst = Part + (size_t)ksp * M_ROWS * 64;
#pragma unroll
    for (int mt = 0; mt < 2; ++mt)
#pragma unroll
        for (int nt = 0; nt < 4; ++nt)
#pragma unroll
            for (int j = 0; j < 4; ++j) {
                int r  = brow + wid * 32 + mt * 16 + (lane >> 4) * 4 + j;
                int cg = nt * 16 + (lane & 15);
                dst[(size_t)r * 64 + cg] = acc[mt][nt][j];
            }
}

// ---------------------------------------------------------------------------
// Causal depthwise conv1d (k=4) + bias + silu; writes bf16 split u (r6 form)
// ---------------------------------------------------------------------------
__global__ __launch_bounds__(256)
void conv_silu_split_kernel(const float* __restrict__ u_raw,
                            const float* __restrict__ W_conv,
                            const float* __restrict__ b_conv,
                            ushortT* __restrict__ Us)
{
    int gid = blockIdx.x * 256 + threadIdx.x;
    if (gid >= M_ROWS * D_MODEL) return;
    int c = gid % D_MODEL;
    int t = (gid / D_MODEL) % SEQ;
    int b = gid / (D_MODEL * SEQ);

    float w0 = W_conv[c * 4 + 0], w1 = W_conv[c * 4 + 1];
    float w2 = W_conv[c * 4 + 2], w3 = W_conv[c * 4 + 3];
    const float* base = u_raw + (size_t)b * SEQ * D_MODEL + c;

    float acc = b_conv[c];
    if (t >= 3) acc = fmaf(base[(size_t)(t - 3) * D_MODEL], w0, acc);
    if (t >= 2) acc = fmaf(base[(size_t)(t - 2) * D_MODEL], w1, acc);
    if (t >= 1) acc = fmaf(base[(size_t)(t - 1) * D_MODEL], w2, acc);
    acc = fmaf(base[(size_t)t * D_MODEL], w3, acc);

    float v = silu_f(acc);

    ushortT hi = f2bf_rne(v);
    ushortT lo = f2bf_rne(v - bf2f(hi));
    size_t row = (size_t)(gid / D_MODEL);
    ushortT* ub = Us + row * KP + c;
    ub[0]           = hi;
    ub[D_MODEL]     = lo;
    ub[2 * D_MODEL] = hi;
}

// ---------------------------------------------------------------------------
// Stage CH rows of x_db into LDS directly from the 4 K-split partials + bias.
// ---------------------------------------------------------------------------
__device__ __forceinline__ void stage_xdb(float* xbl, const float* __restrict__ Part,
                                          const float* __restrict__ b_xp,
                                          size_t rowbase)
{
    const size_t PS = (size_t)M_ROWS * 64;
    for (int idx = threadIdx.x; idx < CH * 48; idx += 256) {
        int t = idx / 48, q = idx % 48;
        size_t prow = (rowbase + t) * 64 + q;
        xbl[idx] = b_xp[q] + Part[prow] + Part[PS + prow]
                 + Part[2 * PS + prow] + Part[3 * PS + prow];
    }
    __syncthreads();
}

// ---------------------------------------------------------------------------
// Scan pass 1: per-chunk local scan from h=0. dt inline (tree-reduced dot);
// x_db staged from partials; fast softplus; __expf dA.
// ---------------------------------------------------------------------------
__global__ __launch_bounds__(256)
void scan_chunk_local(const ushortT* __restrict__ Us,
                      const float* __restrict__ Part,
                      const float* __restrict__ b_xp,
                      const float* __restrict__ A_log,
                      const float* __restrict__ W_dt,
                      const float* __restrict__ b_dt,
                      float* __restrict__ Pbuf,
                      float* __restrict__ Hloc)
{
    __shared__ float xbl[CH * 48];   // 3 KB

    int gid = blockIdx.x * 256 + threadIdx.x;
    int c     = gid % D_MODEL;
    int rem   = gid / D_MODEL;        // block-uniform
    int chunk = rem % NCHUNK;
    int b     = rem / NCHUNK;

    const size_t rowbase = (size_t)b * SEQ + (size_t)chunk * CH;
    stage_xdb(xbl, Part, b_xp, rowbase);

    float a[16], h[16], wdt[16];
#pragma unroll
    for (int i = 0; i < 16; ++i) {
        a[i]   = -__expf(A_log[c * 16 + i]);
        h[i]   = 0.f;
        wdt[i] = W_dt[i * D_MODEL + c];
    }
    const float bdt = b_dt[c];

    float dtsum = 0.f;
    size_t row = rowbase;
    for (int t = 0; t < CH; ++t, ++row) {
        const float* xb = xbl + t * 48;
        // tree-reduced dt dot (4 chains of depth 4)
        float p0 = fmaf(xb[0], wdt[0], bdt);
        float p1 = xb[1] * wdt[1];
        float p2 = xb[2] * wdt[2];
        float p3 = xb[3] * wdt[3];
#pragma unroll
        for (int i = 4; i < 16; i += 4) {
            p0 = fmaf(xb[i + 0], wdt[i + 0], p0);
            p1 = fmaf(xb[i + 1], wdt[i + 1], p1);
            p2 = fmaf(xb[i + 2], wdt[i + 2], p2);
            p3 = fmaf(xb[i + 3], wdt[i + 3], p3);
        }
        float accd = (p0 + p1) + (p2 + p3);
        float e    = __expf(-fabsf(accd));
        float dtv  = fmaxf(accd, 0.0f) + __logf(1.0f + e);

        float uv = bf2f(Us[row * KP + c]) + bf2f(Us[row * KP + D_MODEL + c]);
        float du = dtv * uv;
        dtsum += dtv;
#pragma unroll
        for (int i = 0; i < 16; ++i) {
            float dA = __expf(dtv * a[i]);
            h[i] = fmaf(dA, h[i], du * xb[16 + i]);
        }
    }

    size_t obase = ((size_t)(b * NCHUNK + chunk) * 16) * D_MODEL + c;
#pragma unroll
    for (int i = 0; i < 16; ++i) {
        Pbuf[obase + (size_t)i * D_MODEL] = __expf(a[i] * dtsum);
        Hloc[obase + (size_t)i * D_MODEL] = h[i];
    }
}

// ---------------------------------------------------------------------------
// Scan pass 2: sequential combine over chunks; records entry state Hin.
// ---------------------------------------------------------------------------
__global__ __launch_bounds__(256)
void scan_combine(const float* __restrict__ Pbuf,
                  const float* __restrict__ Hloc,
                  float* __restrict__ Hin)
{
    int gid = blockIdx.x * 256 + threadIdx.x;
    if (gid >= BATCH * 16 * D_MODEL) return;
    int c   = gid % D_MODEL;
    int rem = gid / D_MODEL;
    int i   = rem % 16;
    int b   = rem / 16;

    const size_t stride = (size_t)16 * D_MODEL;
    size_t idx = ((size_t)(b * NCHUNK) * 16 + i) * D_MODEL + c;

    float h  = 0.f;
    float Pn = Pbuf[idx];
    float Hn = Hloc[idx];
    for (int ch = 0; ch < NCHUNK; ++ch) {
        float Pc = Pn, Hc = Hn;
        if (ch + 1 < NCHUNK) {
            Pn = Pbuf[idx + stride];
            Hn = Hloc[idx + stride];
        }
        Hin[idx] = h;
        h = fmaf(Pc, h, Hc);
        idx += stride;
    }
}

// ---------------------------------------------------------------------------
// Scan pass 3: re-run chunk from true entry state; fused gate + bf16 split.
// Tree-reduced dots; x_db staged from partials.
// ---------------------------------------------------------------------------
__global__ __launch_bounds__(256)
void scan_chunk_final(const ushortT* __restrict__ Us,
                      const float* __restrict__ Part,
                      const float* __restrict__ b_xp,
                      const float* __restrict__ A_log,
                      const float* __restrict__ W_dt,
                      const float* __restrict__ b_dt,
                      const float* __restrict__ Hin,
                      const float* __restrict__ z,
                      ushortT* __restrict__ Ys)
{
    __shared__ float xbl[CH * 48];   // 3 KB

    int gid = blockIdx.x * 256 + threadIdx.x;
    int c     = gid % D_MODEL;
    int rem   = gid / D_MODEL;        // block-uniform
    int chunk = rem % NCHUNK;
    int b     = rem / NCHUNK;

    const size_t rowbase = (size_t)b * SEQ + (size_t)chunk * CH;
    stage_xdb(xbl, Part, b_xp, rowbase);

    size_t ibase = ((size_t)(b * NCHUNK + chunk) * 16) * D_MODEL + c;

    float a[16], h[16], wdt[16];
#pragma unroll
    for (int i = 0; i < 16; ++i) {
        a[i]   = -__expf(A_log[c * 16 + i]);
        h[i]   = Hin[ibase + (size_t)i * D_MODEL];
        wdt[i] = W_dt[i * D_MODEL + c];
    }
    const float bdt = b_dt[c];

    size_t row = rowbase;
    for (int t = 0; t < CH; ++t, ++row) {
        const float* xb = xbl + t * 48;
        float p0 = fmaf(xb[0], wdt[0], bdt);
        float p1 = xb[1] * wdt[1];
        float p2 = xb[2] * wdt[2];
        float p3 = xb[3] * wdt[3];
#pragma unroll
        for (int i = 4; i < 16; i += 4) {
            p0 = fmaf(xb[i + 0], wdt[i + 0], p0);
            p1 = fmaf(xb[i + 1], wdt[i + 1], p1);
            p2 = fmaf(xb[i + 2], wdt[i + 2], p2);
            p3 = fmaf(xb[i + 3], wdt[i + 3], p3);
        }
        float accd = (p0 + p1) + (p2 + p3);
        float e    = __expf(-fabsf(accd));
        float dtv  = fmaxf(accd, 0.0f) + __logf(1.0f + e);

        float uv = bf2f(Us[row * KP + c]) + bf2f(Us[row * KP + D_MODEL + c]);
        float du = dtv * uv;

        float y0 = 0.f, y1 = 0.f, y2 = 0.f, y3 = 0.f;
#pragma unroll
        for (int i = 0; i < 16; i += 4) {
            float dA0 = __expf(dtv * a[i + 0]);
            float dA1 = __expf(dtv * a[i + 1]);
            float dA2 = __expf(dtv * a[i + 2]);
            float dA3 = __expf(dtv * a[i + 3]);
            h[i + 0] = fmaf(dA0, h[i + 0], du * xb[16 + i + 0]);
            h[i + 1] = fmaf(dA1, h[i + 1], du * xb[16 + i + 1]);
            h[i + 2] = fmaf(dA2, h[i + 2], du * xb[16 + i + 2]);
            h[i + 3] = fmaf(dA3, h[i + 3], du * xb[16 + i + 3]);
            y0 = fmaf(h[i + 0], xb[32 + i + 0], y0);
            y1 = fmaf(h[i + 1], xb[32 + i + 1], y1);
            y2 = fmaf(h[i + 2], xb[32 + i + 2], y2);
            y3 = fmaf(h[i + 3], xb[32 + i + 3], y3);
        }
        float yv = (y0 + y1) + (y2 + y3);

        float g = yv * silu_f(z[row * D_MODEL + c]);
        ushortT hi = f2bf_rne(g);
        ushortT lo = f2bf_rne(g - bf2f(hi));
        ushortT* yb = Ys + row * KP + c;
        yb[0]           = hi;
        yb[D_MODEL]     = lo;
        yb[2 * D_MODEL] = hi;
    }
}

// ---------------------------------------------------------------------------
extern "C" void kernel_launch(void* const* d_in, const int* in_sizes, int n_in,
                              void* d_out, int out_size, void* d_ws, size_t ws_size,
                              hipStream_t stream)
{
    const float* x      = (const float*)d_in[0];
    const float* W_in   = (const float*)d_in[1];
    const float* b_in   = (const float*)d_in[2];
    const float* W_conv = (const float*)d_in[3];
    const float* b_conv = (const float*)d_in[4];
    const float* W_xp   = (const float*)d_in[5];
    const float* b_xp   = (const float*)d_in[6];
    const float* W_dt   = (const float*)d_in[7];
    const float* b_dt   = (const float*)d_in[8];
    const float* A_log  = (const float*)d_in[9];
    const float* W_out  = (const float*)d_in[10];
    const float* b_out  = (const float*)d_in[11];
    float* out = (float*)d_out;

    // Layout identical to r10 (proven); x_db slot now unused.
    float* ws = (float*)d_ws;
    const size_t S  = (size_t)M_ROWS * D_MODEL;              // 4194304
    const size_t SC = (size_t)BATCH * NCHUNK * 16 * D_MODEL; // 4194304 (CH=16)
    float* u_raw  = ws;                      // [0, S)
    float* z      = ws + S;                  // [S, 2S)
    float* kpart  = ws;                      // overlay [0, 2S) for out-proj
    float* Pbuf   = ws + 2 * S + 196608;
    float* HlocB  = Pbuf + SC;
    float* HinB   = HlocB + SC;
    ushortT* xs   = (ushortT*)(HinB + SC);            // M*KP bf16 (A operand; Us; Ys)
    ushortT* wt   = xs + (size_t)M_ROWS * KP;         // 2048*KP (W_in, later W_out)
    ushortT* wxp  = wt + (size_t)2048 * KP;           // 64*KP
    float*   part = (float*)(wxp + (size_t)64 * KP);  // 4*M*64 fp32

    dim3 blk(256);

    // 0) W_in transpose+split; merged x-split + W_xp-split
    wsplit_t_kernel<<<dim3(2 * D_MODEL / 32, D_MODEL / 32), blk, 0, stream>>>(W_in, wt, 2 * D_MODEL);
    split_x_xp_kernel<<<dim3(M_ROWS + 256), blk, 0, stream>>>(x, W_xp, xs, wxp);

    // 1) xz = x @ W_in + b_in  ->  u_raw | z   (bf16 MFMA, split-K3)
    gemm_mfma_split<<<dim3(2 * D_MODEL / 128, M_ROWS / 128, 1), blk, 0, stream>>>(
        xs, wt, b_in, u_raw, z, 2 * D_MODEL, D_MODEL, KP / 64);

    // 2) conv + silu -> bf16 split Us (into xs, free after GEMM1)
    conv_silu_split_kernel<<<dim3(M_ROWS * D_MODEL / 256), blk, 0, stream>>>(
        u_raw, W_conv, b_conv, xs);

    // 3) x_db partials = u_conv @ W_xp   (MFMA, K-split 4; combine folded into scans)
    gemm_xp_mfma<<<dim3(4, M_ROWS / 128), blk, 0, stream>>>(xs, wxp, part);

    // 4) chunked selective scan (dt inline) -> fused gate+split into xs (Ys)
    scan_chunk_local<<<dim3(BATCH * NCHUNK * D_MODEL / 256), blk, 0, stream>>>(
        xs, part, b_xp, A_log, W_dt, b_dt, Pbuf, HlocB);
    scan_combine<<<dim3(BATCH * 16 * D_MODEL / 256), blk, 0, stream>>>(Pbuf, HlocB, HinB);

    // W_out transpose+split into wt (W_in copy dead after step 1)
    wsplit_t_kernel<<<dim3(D_MODEL / 32, D_MODEL / 32), blk, 0, stream>>>(W_out, wt, D_MODEL);

    scan_chunk_final<<<dim3(BATCH * NCHUNK * D_MODEL / 256), blk, 0, stream>>>(
        xs, part, b_xp, A_log, W_dt, b_dt, HinB, z, xs);

    // 5) out = gated_y @ W_out + b_out   (bf16 MFMA, split-K3, split-K2 grid)
    gemm_mfma_split<<<dim3(D_MODEL / 128, M_ROWS / 128, 2), blk, 0, stream>>>(
        xs, wt, b_out, kpart, kpart, D_MODEL, D_MODEL, KP / 128);
    out_combine_kernel<<<dim3(M_ROWS), blk, 0, stream>>>(kpart, b_out, out);
}

// Round 12
// 215.353 us; speedup vs baseline: 1.0166x; 1.0166x over previous
//
#include <hip/hip_runtime.h>
#include <math.h>

#define D_MODEL 1024
#define D_STATE 16
#define BATCH   2
#define SEQ     2048
#define M_ROWS  (BATCH*SEQ)   // 4096
#define KP      3072          // split K' = 3*1024
#define CH      16            // scan chunk length
#define NCHUNK  (SEQ/CH)      // 128

typedef unsigned short ushortT;
typedef ushortT ushortx4 __attribute__((ext_vector_type(4)));
typedef ushortT ushortx8 __attribute__((ext_vector_type(8)));
typedef short   shortx8  __attribute__((ext_vector_type(8)));
typedef float   f32x4    __attribute__((ext_vector_type(4)));

__device__ __forceinline__ float silu_f(float x) {
    return x / (1.0f + __expf(-x));
}
__device__ __forceinline__ ushortT f2bf_rne(float f) {
    unsigned u = __float_as_uint(f);
    u += 0x7FFF + ((u >> 16) & 1);
    return (ushortT)(u >> 16);
}
__device__ __forceinline__ float bf2f(ushortT h) {
    return __uint_as_float(((unsigned)h) << 16);
}
__device__ __forceinline__ void gload_lds16(const void* g, void* l) {
    __builtin_amdgcn_global_load_lds(
        (const __attribute__((address_space(1))) void*)g,
        (__attribute__((address_space(3))) void*)l, 16, 0, 0);
}

// ---------------------------------------------------------------------------
// Merged prologue elementwise conversions (no LDS, no barriers):
//  blocks [0, M_ROWS)        : x [M][1024] -> Xs [M][3072] (hi|lo|hi)
//  blocks [M_ROWS, M_ROWS+256): W_xp [1024][48] -> wxp [64][3072] (hi|hi|lo)
// ---------------------------------------------------------------------------
__global__ __launch_bounds__(256)
void split_x_xp_kernel(const float* __restrict__ X, const float* __restrict__ W_xp,
                       ushortT* __restrict__ Xs, ushortT* __restrict__ wxp)
{
    const int bid = blockIdx.x;
    const int tid = threadIdx.x;
    if (bid < M_ROWS) {
        int gid = bid * 256 + tid;          // M*256
        int row = gid >> 8, kc = gid & 255;
        float4 v = *reinterpret_cast<const float4*>(X + (size_t)row * D_MODEL + kc * 4);
        float vv[4] = {v.x, v.y, v.z, v.w};
        ushortx4 h, l;
#pragma unroll
        for (int i = 0; i < 4; ++i) {
            ushortT hi = f2bf_rne(vv[i]);
            h[i] = hi;
            l[i] = f2bf_rne(vv[i] - bf2f(hi));
        }
        ushortT* base = Xs + (size_t)row * KP + kc * 4;
        *(ushortx4*)(base)               = h;
        *(ushortx4*)(base + D_MODEL)     = l;
        *(ushortx4*)(base + 2 * D_MODEL) = h;
    } else {
        int gid = (bid - M_ROWS) * 256 + tid;   // 64*1024
        int k = gid & (D_MODEL - 1);
        int n = gid >> 10;
        ushortT hi = 0, lo = 0;
        if (n < 48) {
            float v = W_xp[(size_t)k * 48 + n];
            hi = f2bf_rne(v);
            lo = f2bf_rne(v - bf2f(hi));
        }
        ushortT* base = wxp + (size_t)n * KP + k;
        base[0]           = hi;
        base[D_MODEL]     = hi;
        base[2 * D_MODEL] = lo;
    }
}

// ---------------------------------------------------------------------------
// Weight transpose + split body (identical math to the proven wsplit_t):
// W fp32 [1024][N] -> Wt bf16 [N][3072] = [hi|hi|lo]
// ---------------------------------------------------------------------------
__device__ __forceinline__ void wsplit_body(const float* __restrict__ W,
                                            ushortT* __restrict__ Wt, int N,
                                            int bx, int by, int tid)
{
    __shared__ float tile[32][33];
    const int K = D_MODEL;
    int nb = bx * 32, kb = by * 32;
    int tx = tid & 31;
    int ty = tid >> 5;   // 0..7
#pragma unroll
    for (int i = 0; i < 4; ++i) {
        int k = ty + i * 8;
        tile[k][tx] = W[(size_t)(kb + k) * N + nb + tx];
    }
    __syncthreads();
#pragma unroll
    for (int i = 0; i < 4; ++i) {
        int n = ty + i * 8;
        float v = tile[tx][n];
        ushortT hi = f2bf_rne(v);
        ushortT lo = f2bf_rne(v - bf2f(hi));
        ushortT* base = Wt + (size_t)(nb + n) * KP + kb + tx;
        base[0]     = hi;
        base[K]     = hi;
        base[2 * K] = lo;
    }
}

// z=0: W_in [1024][2048] -> wt; z=1 (x<32): W_out [1024][1024] -> wt2
__global__ __launch_bounds__(256)
void wsplit_both_kernel(const float* __restrict__ W_in,
                        const float* __restrict__ W_out,
                        ushortT* __restrict__ wt, ushortT* __restrict__ wt2)
{
    if (blockIdx.z == 0) {
        wsplit_body(W_in, wt, 2 * D_MODEL, blockIdx.x, blockIdx.y, threadIdx.x);
    } else {
        if (blockIdx.x >= D_MODEL / 32) return;   // uniform per block
        wsplit_body(W_out, wt2, D_MODEL, blockIdx.x, blockIdx.y, threadIdx.x);
    }
}

// ---------------------------------------------------------------------------
// bf16 MFMA GEMM: C = A[M][KP] @ Bt[N][KP]^T (+bias), 128x128 tile, BK=64,
// 4 waves (2x2), 16x16x32 MFMA. global_load_lds dbuf staging.
// gridDim.z==1: bias + split C0|C1 write. gridDim.z>1: K-split partials to C0.
// ---------------------------------------------------------------------------
__global__ __launch_bounds__(256)
void gemm_mfma_split(const ushortT* __restrict__ A,
                     const ushortT* __restrict__ Bt,
                     const float* __restrict__ bias,
                     float* __restrict__ C0,
                     float* __restrict__ C1,
                     int N, int split, int NS)
{
    __shared__ char lds[65536];   // [2 bufs][A 16K | B 16K]

    const int tid  = threadIdx.x;
    const int lane = tid & 63;
    const int wid  = tid >> 6;
    const int wr   = wid >> 1;
    const int wc   = wid & 1;

    const int nwg  = gridDim.x * gridDim.y;
    const int wgid = blockIdx.y * gridDim.x + blockIdx.x;
    const int qc   = nwg >> 3;
    const int swz  = (wgid & 7) * qc + (wgid >> 3);
    const int bx   = swz % gridDim.x;
    const int by   = swz / gridDim.x;
    const int brow = by * 128;
    const int bcol = bx * 128;
    const int kbeg = blockIdx.z * NS * 64;

    f32x4 acc[4][4];
#pragma unroll
    for (int i = 0; i < 4; ++i)
#pragma unroll
        for (int j = 0; j < 4; ++j) {
            acc[i][j][0] = 0.f; acc[i][j][1] = 0.f;
            acc[i][j][2] = 0.f; acc[i][j][3] = 0.f;
        }

    const ushortT* Ag = A  + (size_t)brow * KP + kbeg;
    const ushortT* Bg = Bt + (size_t)bcol * KP + kbeg;

    int off[4], lslot[4];
#pragma unroll
    for (int q = 0; q < 4; ++q) {
        int slot = q * 256 + tid;
        int row = slot >> 3, kc = slot & 7;
        off[q]   = row * KP + ((kc ^ (row & 7)) << 3);
        lslot[q] = (q * 256 + wid * 64) * 16;
    }

#define STAGE(buf, k0)                                                         \
    {                                                                          \
        char* Ad = lds + (buf) * 32768;                                        \
        char* Bd = Ad + 16384;                                                 \
        _Pragma("unroll")                                                      \
        for (int q = 0; q < 4; ++q) {                                          \
            gload_lds16(Ag + off[q] + (k0), Ad + lslot[q]);                    \
            gload_lds16(Bg + off[q] + (k0), Bd + lslot[q]);                    \
        }                                                                      \
    }

#define COMPUTE(buf)                                                           \
    {                                                                          \
        char* Asm = lds + (buf) * 32768;                                       \
        char* Bsm = Asm + 16384;                                               \
        _Pragma("unroll")                                                      \
        for (int ks = 0; ks < 2; ++ks) {                                       \
            shortx8 af[4], bfr[4];                                             \
            _Pragma("unroll")                                                  \
            for (int mt = 0; mt < 4; ++mt) {                                   \
                int row = wr * 64 + mt * 16 + (lane & 15);                     \
                int kc = ks * 4 + (lane >> 4);                                 \
                int byt = row * 128 + ((kc * 16) ^ ((row & 7) << 4));          \
                af[mt] = *(const shortx8*)(Asm + byt);                         \
            }                                                                  \
            _Pragma("unroll")                                                  \
            for (int nt = 0; nt < 4; ++nt) {                                   \
                int row = wc * 64 + nt * 16 + (lane & 15);                     \
                int kc = ks * 4 + (lane >> 4);                                 \
                int byt = row * 128 + ((kc * 16) ^ ((row & 7) << 4));          \
                bfr[nt] = *(const shortx8*)(Bsm + byt);                        \
            }                                                                  \
            _Pragma("unroll")                                                  \
            for (int mt = 0; mt < 4; ++mt)                                     \
                _Pragma("unroll")                                              \
                for (int nt = 0; nt < 4; ++nt)                                 \
                    acc[mt][nt] = __builtin_amdgcn_mfma_f32_16x16x32_bf16(     \
                        af[mt], bfr[nt], acc[mt][nt], 0, 0, 0);                \
        }                                                                      \
    }

    STAGE(0, 0);
    __syncthreads();
    for (int s = 0; s < NS; ++s) {
        const int cur = s & 1;
        if (s + 1 < NS) STAGE(cur ^ 1, (s + 1) * 64);
        COMPUTE(cur);
        __syncthreads();
    }

#undef STAGE
#undef COMPUTE

    if (gridDim.z == 1) {
        const bool inC0  = (bcol < split);
        float* dst       = inC0 ? C0 : C1;
        const int ldc    = inC0 ? split : (N - split);
        const int cb     = bcol - (inC0 ? 0 : split);
#pragma unroll
        for (int mt = 0; mt < 4; ++mt)
#pragma unroll
            for (int nt = 0; nt < 4; ++nt)
#pragma unroll
                for (int j = 0; j < 4; ++j) {
                    int r  = brow + wr * 64 + mt * 16 + (lane >> 4) * 4 + j;
                    int cg = wc * 64 + nt * 16 + (lane & 15);
                    dst[(size_t)r * ldc + cb + cg] = acc[mt][nt][j] + bias[bcol + cg];
                }
    } else {
        float* dst = C0 + (size_t)blockIdx.z * ((size_t)M_ROWS * N);
#pragma unroll
        for (int mt = 0; mt < 4; ++mt)
#pragma unroll
            for (int nt = 0; nt < 4; ++nt)
#pragma unroll
                for (int j = 0; j < 4; ++j) {
                    int r  = brow + wr * 64 + mt * 16 + (lane >> 4) * 4 + j;
                    int cg = wc * 64 + nt * 16 + (lane & 15);
                    dst[(size_t)r * N + bcol + cg] = acc[mt][nt][j];
                }
    }
}

// ---------------------------------------------------------------------------
// out = bias + part0 + part1
// ---------------------------------------------------------------------------
__global__ __launch_bounds__(256)
void out_combine_kernel(const float* __restrict__ part,
                        const float* __restrict__ bias,
                        float* __restrict__ out)
{
    int gid = blockIdx.x * 256 + threadIdx.x;   // M*256
    if (gid >= M_ROWS * 256) return;
    int row = gid >> 8, q = gid & 255;
    size_t i = (size_t)row * D_MODEL + q * 4;
    float4 b  = *reinterpret_cast<const float4*>(bias + q * 4);
    float4 p0 = *reinterpret_cast<const float4*>(part + i);
    float4 p1 = *reinterpret_cast<const float4*>(part + (size_t)M_ROWS * D_MODEL + i);
    float4 r;
    r.x = b.x + p0.x + p1.x; r.y = b.y + p0.y + p1.y;
    r.z = b.z + p0.z + p1.z; r.w = b.w + p0.w + p1.w;
    *reinterpret_cast<float4*>(out + i) = r;
}

// ---------------------------------------------------------------------------
// Skinny MFMA GEMM for x_db: A us[M][KP] @ wxp[64][KP]^T, K-split 4 ways.
// ---------------------------------------------------------------------------
__global__ __launch_bounds__(256)
void gemm_xp_mfma(const ushortT* __restrict__ A,
                  const ushortT* __restrict__ Bt,
                  float* __restrict__ Part)
{
    __shared__ char lds[24576];
    char* Asm = lds;
    char* Bsm = lds + 16384;

    const int tid  = threadIdx.x;
    const int lane = tid & 63;
    const int wid  = tid >> 6;
    const int ksp  = blockIdx.x;
    const int brow = blockIdx.y * 128;
    const int kbase = ksp * (KP / 4);

    f32x4 acc[2][4];
#pragma unroll
    for (int i = 0; i < 2; ++i)
#pragma unroll
        for (int j = 0; j < 4; ++j) {
            acc[i][j][0] = 0.f; acc[i][j][1] = 0.f;
            acc[i][j][2] = 0.f; acc[i][j][3] = 0.f;
        }

    const ushortT* Ag = A  + (size_t)brow * KP + kbase;
    const ushortT* Bg = Bt + kbase;

    for (int s = 0; s < 12; ++s) {
        const int k0 = s * 64;
        ushortx8 ra[4], rb[2];
#pragma unroll
        for (int q = 0; q < 4; ++q) {
            int slot = tid + q * 256;
            int row = slot >> 3, kc = slot & 7;
            ra[q] = *(const ushortx8*)(Ag + (size_t)row * KP + k0 + kc * 8);
        }
#pragma unroll
        for (int q = 0; q < 2; ++q) {
            int slot = tid + q * 256;
            int row = slot >> 3, kc = slot & 7;
            rb[q] = *(const ushortx8*)(Bg + (size_t)row * KP + k0 + kc * 8);
        }
        __syncthreads();
#pragma unroll
        for (int q = 0; q < 4; ++q) {
            int slot = tid + q * 256;
            int row = slot >> 3, kc = slot & 7;
            int byt = row * 128 + ((kc * 16) ^ ((row & 7) << 4));
            *(ushortx8*)(Asm + byt) = ra[q];
        }
#pragma unroll
        for (int q = 0; q < 2; ++q) {
            int slot = tid + q * 256;
            int row = slot >> 3, kc = slot & 7;
            int byt = row * 128 + ((kc * 16) ^ ((row & 7) << 4));
            *(ushortx8*)(Bsm + byt) = rb[q];
        }
        __syncthreads();
#pragma unroll
        for (int ks = 0; ks < 2; ++ks) {
            shortx8 af[2], bfr[4];
#pragma unroll
            for (int mt = 0; mt < 2; ++mt) {
                int row = wid * 32 + mt * 16 + (lane & 15);
                int kc = ks * 4 + (lane >> 4);
                int byt = row * 128 + ((kc * 16) ^ ((row & 7) << 4));
                af[mt] = *(const shortx8*)(Asm + byt);
            }
#pragma unroll
            for (int nt = 0; nt < 4; ++nt) {
                int row = nt * 16 + (lane & 15);
                int kc = ks * 4 + (lane >> 4);
                int byt = row * 128 + ((kc * 16) ^ ((row & 7) << 4));
                bfr[nt] = *(const shortx8*)(Bsm + byt);
            }
#pragma unroll
            for (int mt = 0; mt < 2; ++mt)
#pragma unroll
                for (int nt = 0; nt < 4; ++nt)
                    acc[mt][nt] = __builtin_amdgcn_mfma_f32_16x16x32_bf16(
                        af[mt], bfr[nt], acc[mt][nt], 0, 0, 0);
        }
        __syncthreads();
    }

    float* dst = Part + (size_t)ksp * M_ROWS * 64;
#pragma unroll
    for (int mt = 0; mt < 2; ++mt)
#pragma unroll
        for (int nt = 0; nt < 4; ++nt)
#pragma unroll
            for (int j = 0; j < 4; ++j) {
                int r  = brow + wid * 32 + mt * 16 + (lane >> 4) * 4 + j;
                int cg = nt * 16 + (lane & 15);
                dst[(size_t)r * 64 + cg] = acc[mt][nt][j];
            }
}

// ---------------------------------------------------------------------------
// Causal depthwise conv1d (k=4) + bias + silu; writes bf16 split u (r6 form)
// ---------------------------------------------------------------------------
__global__ __launch_bounds__(256)
void conv_silu_split_kernel(const float* __restrict__ u_raw,
                            const float* __restrict__ W_conv,
                            const float* __restrict__ b_conv,
                            ushortT* __restrict__ Us)
{
    int gid = blockIdx.x * 256 + threadIdx.x;
    if (gid >= M_ROWS * D_MODEL) return;
    int c = gid % D_MODEL;
    int t = (gid / D_MODEL) % SEQ;
    int b = gid / (D_MODEL * SEQ);

    float w0 = W_conv[c * 4 + 0], w1 = W_conv[c * 4 + 1];
    float w2 = W_conv[c * 4 + 2], w3 = W_conv[c * 4 + 3];
    const float* base = u_raw + (size_t)b * SEQ * D_MODEL + c;

    float acc = b_conv[c];
    if (t >= 3) acc = fmaf(base[(size_t)(t - 3) * D_MODEL], w0, acc);
    if (t >= 2) acc = fmaf(base[(size_t)(t - 2) * D_MODEL], w1, acc);
    if (t >= 1) acc = fmaf(base[(size_t)(t - 1) * D_MODEL], w2, acc);
    acc = fmaf(base[(size_t)t * D_MODEL], w3, acc);

    float v = silu_f(acc);

    ushortT hi = f2bf_rne(v);
    ushortT lo = f2bf_rne(v - bf2f(hi));
    size_t row = (size_t)(gid / D_MODEL);
    ushortT* ub = Us + row * KP + c;
    ub[0]           = hi;
    ub[D_MODEL]     = lo;
    ub[2 * D_MODEL] = hi;
}

// ---------------------------------------------------------------------------
// Stage CH rows of x_db into LDS directly from the 4 K-split partials + bias.
// ---------------------------------------------------------------------------
__device__ __forceinline__ void stage_xdb(float* xbl, const float* __restrict__ Part,
                                          const float* __restrict__ b_xp,
                                          size_t rowbase)
{
    const size_t PS = (size_t)M_ROWS * 64;
    for (int idx = threadIdx.x; idx < CH * 48; idx += 256) {
        int t = idx / 48, q = idx % 48;
        size_t prow = (rowbase + t) * 64 + q;
        xbl[idx] = b_xp[q] + Part[prow] + Part[PS + prow]
                 + Part[2 * PS + prow] + Part[3 * PS + prow];
    }
    __syncthreads();
}

// ---------------------------------------------------------------------------
// Scan pass 1: per-chunk local scan from h=0. dt inline (tree-reduced dot);
// stores dtsum (P recomputed in combine) + Hloc.
// ---------------------------------------------------------------------------
__global__ __launch_bounds__(256)
void scan_chunk_local(const ushortT* __restrict__ Us,
                      const float* __restrict__ Part,
                      const float* __restrict__ b_xp,
                      const float* __restrict__ A_log,
                      const float* __restrict__ W_dt,
                      const float* __restrict__ b_dt,
                      float* __restrict__ Dsum,
                      float* __restrict__ Hloc)
{
    __shared__ float xbl[CH * 48];   // 3 KB

    int gid = blockIdx.x * 256 + threadIdx.x;
    int c     = gid % D_MODEL;
    int rem   = gid / D_MODEL;        // block-uniform
    int chunk = rem % NCHUNK;
    int b     = rem / NCHUNK;

    const size_t rowbase = (size_t)b * SEQ + (size_t)chunk * CH;
    stage_xdb(xbl, Part, b_xp, rowbase);

    float a[16], h[16], wdt[16];
#pragma unroll
    for (int i = 0; i < 16; ++i) {
        a[i]   = -__expf(A_log[c * 16 + i]);
        h[i]   = 0.f;
        wdt[i] = W_dt[i * D_MODEL + c];
    }
    const float bdt = b_dt[c];

    float dtsum = 0.f;
    size_t row = rowbase;
    for (int t = 0; t < CH; ++t, ++row) {
        const float* xb = xbl + t * 48;
        float p0 = fmaf(xb[0], wdt[0], bdt);
        float p1 = xb[1] * wdt[1];
        float p2 = xb[2] * wdt[2];
        float p3 = xb[3] * wdt[3];
#pragma unroll
        for (int i = 4; i < 16; i += 4) {
            p0 = fmaf(xb[i + 0], wdt[i + 0], p0);
            p1 = fmaf(xb[i + 1], wdt[i + 1], p1);
            p2 = fmaf(xb[i + 2], wdt[i + 2], p2);
            p3 = fmaf(xb[i + 3], wdt[i + 3], p3);
        }
        float accd = (p0 + p1) + (p2 + p3);
        float e    = __expf(-fabsf(accd));
        float dtv  = fmaxf(accd, 0.0f) + __logf(1.0f + e);

        float uv = bf2f(Us[row * KP + c]) + bf2f(Us[row * KP + D_MODEL + c]);
        float du = dtv * uv;
        dtsum += dtv;
#pragma unroll
        for (int i = 0; i < 16; ++i) {
            float dA = __expf(dtv * a[i]);
            h[i] = fmaf(dA, h[i], du * xb[16 + i]);
        }
    }

    Dsum[((size_t)(b * NCHUNK + chunk)) * D_MODEL + c] = dtsum;
    size_t obase = ((size_t)(b * NCHUNK + chunk) * 16) * D_MODEL + c;
#pragma unroll
    for (int i = 0; i < 16; ++i)
        Hloc[obase + (size_t)i * D_MODEL] = h[i];
}

// ---------------------------------------------------------------------------
// Scan pass 2: sequential combine over chunks; P recomputed from dtsum;
// records entry state Hin.
// ---------------------------------------------------------------------------
__global__ __launch_bounds__(256)
void scan_combine(const float* __restrict__ Dsum,
                  const float* __restrict__ Hloc,
                  const float* __restrict__ A_log,
                  float* __restrict__ Hin)
{
    int gid = blockIdx.x * 256 + threadIdx.x;
    if (gid >= BATCH * 16 * D_MODEL) return;
    int c   = gid % D_MODEL;
    int rem = gid / D_MODEL;
    int i   = rem % 16;
    int b   = rem / 16;

    const float a = -__expf(A_log[c * 16 + i]);   // same expr as scan_local

    const size_t strideH = (size_t)16 * D_MODEL;
    size_t idxH = ((size_t)(b * NCHUNK) * 16 + i) * D_MODEL + c;
    size_t idxD = (size_t)(b * NCHUNK) * D_MODEL + c;

    float h  = 0.f;
    float Dn = Dsum[idxD];
    float Hn = Hloc[idxH];
    for (int ch = 0; ch < NCHUNK; ++ch) {
        float Dc = Dn, Hc = Hn;
        if (ch + 1 < NCHUNK) {
            Dn = Dsum[idxD + D_MODEL];
            Hn = Hloc[idxH + strideH];
        }
        Hin[idxH] = h;
        h = fmaf(__expf(a * Dc), h, Hc);
        idxH += strideH;
        idxD += D_MODEL;
    }
}

// ---------------------------------------------------------------------------
// Scan pass 3: re-run chunk from true entry state; fused gate + bf16 split.
// ---------------------------------------------------------------------------
__global__ __launch_bounds__(256)
void scan_chunk_final(const ushortT* __restrict__ Us,
                      const float* __restrict__ Part,
                      const float* __restrict__ b_xp,
                      const float* __restrict__ A_log,
                      const float* __restrict__ W_dt,
                      const float* __restrict__ b_dt,
                      const float* __restrict__ Hin,
                      const float* __restrict__ z,
                      ushortT* __restrict__ Ys)
{
    __shared__ float xbl[CH * 48];   // 3 KB

    int gid = blockIdx.x * 256 + threadIdx.x;
    int c     = gid % D_MODEL;
    int rem   = gid / D_MODEL;        // block-uniform
    int chunk = rem % NCHUNK;
    int b     = rem / NCHUNK;

    const size_t rowbase = (size_t)b * SEQ + (size_t)chunk * CH;
    stage_xdb(xbl, Part, b_xp, rowbase);

    size_t ibase = ((size_t)(b * NCHUNK + chunk) * 16) * D_MODEL + c;

    float a[16], h[16], wdt[16];
#pragma unroll
    for (int i = 0; i < 16; ++i) {
        a[i]   = -__expf(A_log[c * 16 + i]);
        h[i]   = Hin[ibase + (size_t)i * D_MODEL];
        wdt[i] = W_dt[i * D_MODEL + c];
    }
    const float bdt = b_dt[c];

    size_t row = rowbase;
    for (int t = 0; t < CH; ++t, ++row) {
        const float* xb = xbl + t * 48;
        float p0 = fmaf(xb[0], wdt[0], bdt);
        float p1 = xb[1] * wdt[1];
        float p2 = xb[2] * wdt[2];
        float p3 = xb[3] * wdt[3];
#pragma unroll
        for (int i = 4; i < 16; i += 4) {
            p0 = fmaf(xb[i + 0], wdt[i + 0], p0);
            p1 = fmaf(xb[i + 1], wdt[i + 1], p1);
            p2 = fmaf(xb[i + 2], wdt[i + 2], p2);
            p3 = fmaf(xb[i + 3], wdt[i + 3], p3);
        }
        float accd = (p0 + p1) + (p2 + p3);
        float e    = __expf(-fabsf(accd));
        float dtv  = fmaxf(accd, 0.0f) + __logf(1.0f + e);

        float uv = bf2f(Us[row * KP + c]) + bf2f(Us[row * KP + D_MODEL + c]);
        float du = dtv * uv;

        float y0 = 0.f, y1 = 0.f, y2 = 0.f, y3 = 0.f;
#pragma unroll
        for (int i = 0; i < 16; i += 4) {
            float dA0 = __expf(dtv * a[i + 0]);
            float dA1 = __expf(dtv * a[i + 1]);
            float dA2 = __expf(dtv * a[i + 2]);
            float dA3 = __expf(dtv * a[i + 3]);
            h[i + 0] = fmaf(dA0, h[i + 0], du * xb[16 + i + 0]);
            h[i + 1] = fmaf(dA1, h[i + 1], du * xb[16 + i + 1]);
            h[i + 2] = fmaf(dA2, h[i + 2], du * xb[16 + i + 2]);
            h[i + 3] = fmaf(dA3, h[i + 3], du * xb[16 + i + 3]);
            y0 = fmaf(h[i + 0], xb[32 + i + 0], y0);
            y1 = fmaf(h[i + 1], xb[32 + i + 1], y1);
            y2 = fmaf(h[i + 2], xb[32 + i + 2], y2);
            y3 = fmaf(h[i + 3], xb[32 + i + 3], y3);
        }
        float yv = (y0 + y1) + (y2 + y3);

        float g = yv * silu_f(z[row * D_MODEL + c]);
        ushortT hi = f2bf_rne(g);
        ushortT lo = f2bf_rne(g - bf2f(hi));
        ushortT* yb = Ys + row * KP + c;
        yb[0]           = hi;
        yb[D_MODEL]     = lo;
        yb[2 * D_MODEL] = hi;
    }
}

// ---------------------------------------------------------------------------
extern "C" void kernel_launch(void* const* d_in, const int* in_sizes, int n_in,
                              void* d_out, int out_size, void* d_ws, size_t ws_size,
                              hipStream_t stream)
{
    const float* x      = (const float*)d_in[0];
    const float* W_in   = (const float*)d_in[1];
    const float* b_in   = (const float*)d_in[2];
    const float* W_conv = (const float*)d_in[3];
    const float* b_conv = (const float*)d_in[4];
    const float* W_xp   = (const float*)d_in[5];
    const float* b_xp   = (const float*)d_in[6];
    const float* W_dt   = (const float*)d_in[7];
    const float* b_dt   = (const float*)d_in[8];
    const float* A_log  = (const float*)d_in[9];
    const float* W_out  = (const float*)d_in[10];
    const float* b_out  = (const float*)d_in[11];
    float* out = (float*)d_out;

    // Layout (~133.4 MB peak < proven 135.4). kpart overlays u_raw+z.
    float* ws = (float*)d_ws;
    const size_t S  = (size_t)M_ROWS * D_MODEL;              // 4194304
    const size_t SC = (size_t)BATCH * NCHUNK * 16 * D_MODEL; // 4194304 (CH=16)
    float* u_raw  = ws;                      // [0, S)
    float* z      = ws + S;                  // [S, 2S)
    float* kpart  = ws;                      // overlay [0, 2S) for out-proj
    float* Dsum   = ws + 2 * S + 196608;     // 262144 floats (in old Pbuf slot)
    float* HlocB  = Dsum + SC;               // keep SC spacing (offsets unchanged)
    float* HinB   = HlocB + SC;
    ushortT* xs   = (ushortT*)(HinB + SC);            // M*KP bf16 (A operand; Us; Ys)
    ushortT* wt   = xs + (size_t)M_ROWS * KP;         // 2048*KP  (W_in)
    ushortT* wxp  = wt + (size_t)2048 * KP;           // 64*KP
    ushortT* wt2  = wxp + (size_t)64 * KP;            // 1024*KP  (W_out)
    float*   part = (float*)(wt2 + (size_t)1024 * KP);// 4*M*64 fp32

    dim3 blk(256);

    // 0) both weight transposes (one launch) + merged x/W_xp split
    wsplit_both_kernel<<<dim3(2 * D_MODEL / 32, D_MODEL / 32, 2), blk, 0, stream>>>(
        W_in, W_out, wt, wt2);
    split_x_xp_kernel<<<dim3(M_ROWS + 256), blk, 0, stream>>>(x, W_xp, xs, wxp);

    // 1) xz = x @ W_in + b_in  ->  u_raw | z   (bf16 MFMA, split-K3)
    gemm_mfma_split<<<dim3(2 * D_MODEL / 128, M_ROWS / 128, 1), blk, 0, stream>>>(
        xs, wt, b_in, u_raw, z, 2 * D_MODEL, D_MODEL, KP / 64);

    // 2) conv + silu -> bf16 split Us (into xs, free after GEMM1)
    conv_silu_split_kernel<<<dim3(M_ROWS * D_MODEL / 256), blk, 0, stream>>>(
        u_raw, W_conv, b_conv, xs);

    // 3) x_db partials = u_conv @ W_xp   (MFMA, K-split 4; combine folded into scans)
    gemm_xp_mfma<<<dim3(4, M_ROWS / 128), blk, 0, stream>>>(xs, wxp, part);

    // 4) chunked selective scan (dt inline) -> fused gate+split into xs (Ys)
    scan_chunk_local<<<dim3(BATCH * NCHUNK * D_MODEL / 256), blk, 0, stream>>>(
        xs, part, b_xp, A_log, W_dt, b_dt, Dsum, HlocB);
    scan_combine<<<dim3(BATCH * 16 * D_MODEL / 256), blk, 0, stream>>>(
        Dsum, HlocB, A_log, HinB);
    scan_chunk_final<<<dim3(BATCH * NCHUNK * D_MODEL / 256), blk, 0, stream>>>(
        xs, part, b_xp, A_log, W_dt, b_dt, HinB, z, xs);

    // 5) out = gated_y @ W_out + b_out   (bf16 MFMA, split-K3, split-K2 grid)
    gemm_mfma_split<<<dim3(D_MODEL / 128, M_ROWS / 128, 2), blk, 0, stream>>>(
        xs, wt2, b_out, kpart, kpart, D_MODEL, D_MODEL, KP / 128);
    out_combine_kernel<<<dim3(M_ROWS), blk, 0, stream>>>(kpart, b_out, out);
}